// Round 7
// baseline (328.413 us; speedup 1.0000x reference)
//
#include <hip/hip_runtime.h>

#define S_LEN 2048
#define DIMSZ 3072
#define NHEAD 24
#define HDIM 128
#define NQKV 9216
#define QSCALE 0.08838834764831845f
#define FMAX 12.0f

typedef unsigned short u16;
typedef unsigned int u32;
typedef __attribute__((ext_vector_type(8))) short short8;
typedef __attribute__((ext_vector_type(4))) float f32x4;

__device__ __forceinline__ u16 f2bf(float f) {
    u32 u = __float_as_uint(f);
    u32 r = (u + 0x7fffu + ((u >> 16) & 1u)) >> 16;
    return (u16)r;
}
__device__ __forceinline__ float bf2f(u16 u) {
    return __uint_as_float((u32)u << 16);
}

__device__ __forceinline__ void lds16(u16* lds, const u16* g) {
    __builtin_amdgcn_global_load_lds((const __attribute__((address_space(1))) u32*)g,
                                     (__attribute__((address_space(3))) u32*)lds, 16, 0, 0);
}

// ---------------- conversion kernels ----------------
__global__ void k_f2bf4(const float4* __restrict__ src, u16* __restrict__ dst, int n4) {
    int i = blockIdx.x * blockDim.x + threadIdx.x;
    if (i >= n4) return;
    float4 v = src[i];
    u32 lo = (u32)f2bf(v.x) | ((u32)f2bf(v.y) << 16);
    u32 hi = (u32)f2bf(v.z) | ((u32)f2bf(v.w) << 16);
    uint2 p; p.x = lo; p.y = hi;
    *(uint2*)(dst + (size_t)i * 4) = p;
}

// ---------------- QKV GEMM: C[m][n] = sum_k A[m][k]*W[n][k], C bf16 ----------------
// Tile 128x192, BK=32 -> grid 16x48 = 768 blocks = 3/CU (cap 4 at 40KB LDS).
// 4 waves (2M x 2N), wave = 64 x 96 = acc[4][6]. Per tile: 10 ds_read_b128 + 24 MFMA.
// 3 independent blocks/CU provide MFMA/LDS overlap; small tiles shrink serial chunks.
// Stage T+2 into just-consumed buffer after closing barrier; counted vmcnt(5).
__global__ __launch_bounds__(256, 2) void k_gemm(const u16* __restrict__ A, const u16* __restrict__ W,
                                                 u16* __restrict__ C) {
    __shared__ __align__(16) u16 As[2][128 * 32]; // 8 KB each
    __shared__ __align__(16) u16 Bs[2][192 * 32]; // 12 KB each
    const int tid = threadIdx.x, wave = tid >> 6, lane = tid & 63;
    const int bm = blockIdx.x / 48, bn = blockIdx.x % 48; // consecutive blocks share bm (A panel)
    const int wm = wave >> 1, wn = wave & 1;              // 2M x 2N
    const int frow = lane & 15, fk = lane >> 4;
    const u16* baseA = A + (size_t)(bm * 128) * DIMSZ;
    const u16* baseW = W + (size_t)(bn * 192) * DIMSZ;

    auto stage = [&](int b, int kt) { // A: 2 loads, B: 3 loads per thread
#pragma unroll
        for (int j = 0; j < 2; ++j) {
            int flat = j * 256 + tid, row = flat >> 2, ch = flat & 3;
            lds16(&As[b][flat * 8], baseA + (size_t)row * DIMSZ + kt * 32 + ((ch ^ ((row >> 1) & 3)) * 8));
        }
#pragma unroll
        for (int j = 0; j < 3; ++j) {
            int flat = j * 256 + tid, row = flat >> 2, ch = flat & 3;
            lds16(&Bs[b][flat * 8], baseW + (size_t)row * DIMSZ + kt * 32 + ((ch ^ ((row >> 1) & 3)) * 8));
        }
    };

    // prologue: tiles 0,1 (5 loads each)
    stage(0, 0); stage(1, 1);
    asm volatile("s_waitcnt vmcnt(5)"); // tile 0's 5 landed
    __builtin_amdgcn_s_barrier();

    f32x4 acc[4][6] = {};
    for (int T = 0; T < 96; ++T) {
        const int b = T & 1;
        const u16* LA = As[b];
        const u16* LB = Bs[b];
        short8 af[4], bf[6];
#pragma unroll
        for (int mf = 0; mf < 4; ++mf) {
            int row = wm * 64 + mf * 16 + frow;
            af[mf] = *(const short8*)&LA[row * 32 + ((fk ^ ((row >> 1) & 3)) * 8)];
        }
#pragma unroll
        for (int nf = 0; nf < 6; ++nf) {
            int row = wn * 96 + nf * 16 + frow;
            bf[nf] = *(const short8*)&LB[row * 32 + ((fk ^ ((row >> 1) & 3)) * 8)];
        }
        __builtin_amdgcn_s_barrier();
        __builtin_amdgcn_s_setprio(1);
#pragma unroll
        for (int mf = 0; mf < 4; ++mf)
#pragma unroll
            for (int nf = 0; nf < 6; ++nf)
                acc[mf][nf] = __builtin_amdgcn_mfma_f32_16x16x32_bf16(af[mf], bf[nf], acc[mf][nf], 0, 0, 0);
        __builtin_amdgcn_s_setprio(0);
        __builtin_amdgcn_s_barrier(); // all reads of buf b done
        if (T < 94) {
            stage(b, T + 2);                     // buffer fully consumed, safe
            asm volatile("s_waitcnt vmcnt(5)");  // tile T+1's loads landed (counted)
            __builtin_amdgcn_s_barrier();
        } else if (T == 94) {
            asm volatile("s_waitcnt vmcnt(0)");
            __builtin_amdgcn_s_barrier();
        }
    }

    // epilogue: bf16 C
#pragma unroll
    for (int mf = 0; mf < 4; ++mf) {
#pragma unroll
        for (int nf = 0; nf < 6; ++nf) {
            int n = bn * 192 + wn * 96 + nf * 16 + frow;
#pragma unroll
            for (int i = 0; i < 4; ++i) {
                int m = bm * 128 + wm * 64 + mf * 16 + fk * 4 + i;
                C[(size_t)m * NQKV + n] = f2bf(acc[mf][nf][i]);
            }
        }
    }
}

// ---------------- postprocess: bias + RMSNorm + RoPE + layout (reads bf16 qkv) --------
__global__ void k_post(const u16* __restrict__ qkv, const float* __restrict__ nw_q,
                       const float* __restrict__ nw_k, const float* __restrict__ bq,
                       const float* __restrict__ bk, const float* __restrict__ bv,
                       const float* __restrict__ cosT, const float* __restrict__ sinT,
                       u16* __restrict__ Qb, u16* __restrict__ Kb, u16* __restrict__ Vt) {
    const int wave = threadIdx.x >> 6, lane = threadIdx.x & 63;
    const int s = blockIdx.x * 4 + wave;
    const int h = blockIdx.y;
    const int d0 = 2 * lane, d1 = 2 * lane + 1;
    const float c = cosT[s * HDIM + d0], sn = sinT[s * HDIM + d0];
    const u16* r0 = qkv + (size_t)s * NQKV + h * HDIM;
    // Q
    {
        float x0 = bf2f(r0[d0]) + bq[h * HDIM + d0];
        float x1 = bf2f(r0[d1]) + bq[h * HDIM + d1];
        float ss = x0 * x0 + x1 * x1;
        for (int m = 1; m < 64; m <<= 1) ss += __shfl_xor(ss, m);
        float r = rsqrtf(ss * (1.0f / 128.0f) + 1e-6f);
        x0 *= r * nw_q[d0]; x1 *= r * nw_q[d1];
        float o0 = (x0 * c - x1 * sn) * QSCALE;
        float o1 = (x1 * c + x0 * sn) * QSCALE;
        u32 p = (u32)f2bf(o0) | ((u32)f2bf(o1) << 16);
        *(u32*)&Qb[((size_t)h * S_LEN + s) * HDIM + d0] = p;
    }
    // K
    {
        float x0 = bf2f(r0[3072 + d0]) + bk[h * HDIM + d0];
        float x1 = bf2f(r0[3072 + d1]) + bk[h * HDIM + d1];
        float ss = x0 * x0 + x1 * x1;
        for (int m = 1; m < 64; m <<= 1) ss += __shfl_xor(ss, m);
        float r = rsqrtf(ss * (1.0f / 128.0f) + 1e-6f);
        x0 *= r * nw_k[d0]; x1 *= r * nw_k[d1];
        float o0 = x0 * c - x1 * sn;
        float o1 = x1 * c + x0 * sn;
        u32 p = (u32)f2bf(o0) | ((u32)f2bf(o1) << 16);
        *(u32*)&Kb[((size_t)h * S_LEN + s) * HDIM + d0] = p;
    }
    // V (transposed)
    {
        float v0 = bf2f(r0[6144 + d0]) + bv[h * HDIM + d0];
        float v1 = bf2f(r0[6144 + d1]) + bv[h * HDIM + d1];
        Vt[((size_t)h * HDIM + d0) * S_LEN + s] = f2bf(v0);
        Vt[((size_t)h * HDIM + d1) * S_LEN + s] = f2bf(v1);
    }
}

// ---------------- flash attention, KV-split x2 (fixed-max softmax -> exact partials) ----
// block = (h, qb, half): 16 KV tiles. Writes unnormalized oP and row-sum lP.
__global__ __launch_bounds__(256, 2) void k_attn(const u16* __restrict__ Qb, const u16* __restrict__ Kb,
                                                 const u16* __restrict__ Vt, float* __restrict__ oP,
                                                 float* __restrict__ lP) {
    __shared__ __align__(16) u16 Ks[2][64 * 128];   // [key][d], chunk ^= row&15
    __shared__ __align__(16) u16 Vs[2][128 * 64];   // [d][key], chunk ^= row&7
    __shared__ __align__(16) u16 Ps[4][32 * 64];    // per-wave P, chunk ^= row&7
    const int wave = threadIdx.x >> 6, lane = threadIdx.x & 63;
    const int half = blockIdx.x & 1, unit = blockIdx.x >> 1;
    const int h = unit >> 4, qb = unit & 15;
    const int kt0 = half * 16;
    const int frow = lane & 15, fk = lane >> 4;

    short8 qf[2][4];
#pragma unroll
    for (int qg = 0; qg < 2; ++qg) {
        const u16* qbase = Qb + ((size_t)h * S_LEN + qb * 128 + wave * 32 + qg * 16 + frow) * HDIM + fk * 8;
#pragma unroll
        for (int ks = 0; ks < 4; ++ks) qf[qg][ks] = *(const short8*)(qbase + ks * 32);
    }

    f32x4 o[2][8] = {};
    float l_p[2][4] = {};

#define STAGE(buf, kt)                                                                       \
    {                                                                                        \
        _Pragma("unroll") for (int c = 0; c < 4; ++c) {                                      \
            int fi = (wave * 4 + c) * 64 + lane;                                             \
            {                                                                                \
                int r = fi >> 4, ch = fi & 15;                                               \
                lds16(Ks[buf] + (wave * 4 + c) * 512,                                        \
                      Kb + ((size_t)h * S_LEN + (kt) * 64 + r) * HDIM + ((ch ^ (r & 15)) * 8)); \
            }                                                                                \
            {                                                                                \
                int r = fi >> 3, ch = fi & 7;                                                \
                lds16(Vs[buf] + (wave * 4 + c) * 512,                                        \
                      Vt + ((size_t)h * HDIM + r) * S_LEN + (kt) * 64 + ((ch ^ (r & 7)) * 8)); \
            }                                                                                \
        }                                                                                    \
    }

    STAGE(0, kt0);
    __syncthreads();
    int cur = 0;

    for (int kt = kt0; kt < kt0 + 16; ++kt) {
        if (kt + 1 < kt0 + 16) STAGE(cur ^ 1, kt + 1);
        f32x4 sacc[2][4] = {};
#pragma unroll
        for (int nf = 0; nf < 4; ++nf) {
#pragma unroll
            for (int ks = 0; ks < 4; ++ks) {
                short8 kf = *(const short8*)&Ks[cur][(nf * 16 + frow) * 128 + (((ks * 4 + fk) ^ frow) & 15) * 8];
#pragma unroll
                for (int qg = 0; qg < 2; ++qg)
                    sacc[qg][nf] = __builtin_amdgcn_mfma_f32_16x16x32_bf16(qf[qg][ks], kf, sacc[qg][nf], 0, 0, 0);
            }
        }
#pragma unroll
        for (int qg = 0; qg < 2; ++qg)
#pragma unroll
            for (int nf = 0; nf < 4; ++nf)
#pragma unroll
                for (int i = 0; i < 4; ++i) {
                    float p = __expf(sacc[qg][nf][i] - FMAX);
                    l_p[qg][i] += p;
                    int row = qg * 16 + fk * 4 + i, col = nf * 16 + frow;
                    Ps[wave][row * 64 + (((col >> 3) ^ (row & 7)) << 3) + (col & 7)] = f2bf(p);
                }
#pragma unroll
        for (int ks = 0; ks < 2; ++ks) {
            short8 pf[2];
#pragma unroll
            for (int qg = 0; qg < 2; ++qg)
                pf[qg] = *(const short8*)&Ps[wave][(qg * 16 + frow) * 64 + (((ks * 4 + fk) ^ (frow & 7)) & 7) * 8];
#pragma unroll
            for (int nf8 = 0; nf8 < 8; ++nf8) {
                short8 vf = *(const short8*)&Vs[cur][(nf8 * 16 + frow) * 64 + (((ks * 4 + fk) ^ (frow & 7)) & 7) * 8];
#pragma unroll
                for (int qg = 0; qg < 2; ++qg)
                    o[qg][nf8] = __builtin_amdgcn_mfma_f32_16x16x32_bf16(pf[qg], vf, o[qg][nf8], 0, 0, 0);
            }
        }
        __syncthreads();
        cur ^= 1;
    }
#undef STAGE

#pragma unroll
    for (int msk = 1; msk < 16; msk <<= 1)
#pragma unroll
        for (int qg = 0; qg < 2; ++qg)
#pragma unroll
            for (int i = 0; i < 4; ++i) l_p[qg][i] += __shfl_xor(l_p[qg][i], msk);

    float* oH = oP + (size_t)half * S_LEN * DIMSZ;
#pragma unroll
    for (int qg = 0; qg < 2; ++qg)
#pragma unroll
        for (int nf8 = 0; nf8 < 8; ++nf8)
#pragma unroll
            for (int i = 0; i < 4; ++i) {
                int srow = qb * 128 + wave * 32 + qg * 16 + fk * 4 + i;
                oH[(size_t)srow * DIMSZ + h * HDIM + nf8 * 16 + frow] = o[qg][nf8][i];
            }
    if (frow == 0) {
#pragma unroll
        for (int qg = 0; qg < 2; ++qg)
#pragma unroll
            for (int i = 0; i < 4; ++i) {
                int srow = qb * 128 + wave * 32 + qg * 16 + fk * 4 + i;
                lP[(size_t)half * NHEAD * S_LEN + h * S_LEN + srow] = l_p[qg][i];
            }
    }
}

// ---------------- combine: out = (o0+o1)/(l0+l1) ----------------
__global__ void k_fin(const float* __restrict__ oP, const float* __restrict__ lP,
                      float* __restrict__ out) {
    int idx = blockIdx.x * 256 + threadIdx.x; // over 2048*3072
    int s = idx / DIMSZ, hd = idx - s * DIMSZ, h = hd >> 7;
    float l = lP[h * S_LEN + s] + lP[NHEAD * S_LEN + h * S_LEN + s];
    out[idx] = (oP[idx] + oP[(size_t)S_LEN * DIMSZ + idx]) / l;
}

// ---------------- launch ----------------
extern "C" void kernel_launch(void* const* d_in, const int* in_sizes, int n_in,
                              void* d_out, int out_size, void* d_ws, size_t ws_size,
                              hipStream_t stream) {
    const float* hs = (const float*)d_in[0];
    const float* wq = (const float*)d_in[1];
    const float* bq = (const float*)d_in[2];
    const float* wk = (const float*)d_in[3];
    const float* bk = (const float*)d_in[4];
    const float* wv = (const float*)d_in[5];
    const float* bv = (const float*)d_in[6];
    const float* nq = (const float*)d_in[7];
    const float* nk = (const float*)d_in[8];
    const float* cosT = (const float*)d_in[9];
    const float* sinT = (const float*)d_in[10];
    float* out = (float*)d_out;

    char* ws = (char*)d_ws;
    u16* hs_b = (u16*)(ws);                      // 12,582,912
    u16* w_b = (u16*)(ws + 12582912);            // 56,623,104
    u16* qkv = (u16*)(ws + 69206016);            // 37,748,736
    u16* Qb = (u16*)(ws + 106954752);            // 12,582,912
    u16* Kb = (u16*)(ws + 119537664);            // 12,582,912
    u16* Vt = (u16*)(ws + 132120576);            // 12,582,912
    float* oP = (float*)(ws + 144703488);        // 50,331,648
    float* lP = (float*)(ws + 195035136);        // 393,216 -> total 195,428,352 B

    k_f2bf4<<<6144, 256, 0, stream>>>((const float4*)hs, hs_b, 1572864);
    k_f2bf4<<<9216, 256, 0, stream>>>((const float4*)wq, w_b, 2359296);
    k_f2bf4<<<9216, 256, 0, stream>>>((const float4*)wk, w_b + 9437184, 2359296);
    k_f2bf4<<<9216, 256, 0, stream>>>((const float4*)wv, w_b + 18874368, 2359296);

    // QKV projection: 768 blocks (16 bm x 48 bn), 3 blocks/CU
    k_gemm<<<dim3(768), 256, 0, stream>>>(hs_b, w_b, qkv);

    k_post<<<dim3(512, 24), 256, 0, stream>>>(qkv, nq, nk, bq, bk, bv, cosT, sinT, Qb, Kb, Vt);

    // attention: 768 blocks = (24 heads x 16 qb) x 2 KV-halves
    k_attn<<<dim3(768), 256, 0, stream>>>(Qb, Kb, Vt, oP, lP);
    k_fin<<<dim3(24576), 256, 0, stream>>>(oP, lP, out);
}